// Round 15
// baseline (323.049 us; speedup 1.0000x reference)
//
#include <hip/hip_runtime.h>
#include <hip/hip_bf16.h>

#define H 4
#define C 64
#define D 256
#define NEG_SLOPE 0.2f
#define ESHIFT 8.0f

typedef _Float16 half_t;
typedef __attribute__((ext_vector_type(8))) _Float16 half8v;
typedef __attribute__((ext_vector_type(4))) float f32x4;

// Layouts:
//  - A / h ("xt"): fragment-linear tiled. panel = 16 rows; half-offset(r,c) =
//    (c>>5)*512 + ((c>>3)&3)*128 + r*8 + (c&7); wave frag load = panel*4096 + s*512 + lane*8.
//  - hp: HEAD-MAJOR hp[h][n][64] (per-head slab 2.56MB fits one XCD 4MiB L2).
//  - a_s / a_d: NODE-MAJOR [n][4].  alpha: HEAD-MAJOR [h][Etot] (csr slot order).

// c_lo += f16lo(w)*a; c_hi += f16hi(w)*a  -- exact f32 fma with f16 source
__device__ inline void fma_mix_pair(float& clo, float& chi, unsigned wu, float a) {
    asm("v_fma_mix_f32 %0, %2, %3, %0 op_sel_hi:[1,0,0]\n\t"
        "v_fma_mix_f32 %1, %2, %3, %1 op_sel:[1,0,0] op_sel_hi:[1,0,0]"
        : "+v"(clo), "+v"(chi)
        : "v"(wu), "v"(a));
}

// ---------------- CSR build ----------------
__global__ void count_kernel(const int* __restrict__ ei, int E, int N, int* __restrict__ counts) {
    int i = blockIdx.x * blockDim.x + threadIdx.x;
    if (i >= E + N) return;
    int d = (i < E) ? ei[E + i] : (i - E);
    atomicAdd(&counts[d], 1);
}

__global__ __launch_bounds__(1024) void scan1(const int* __restrict__ counts,
                                              int* __restrict__ row_ptr,
                                              int* __restrict__ bsum, int N) {
    __shared__ int wsum[16];
    int tid = threadIdx.x, lane = tid & 63, wid = tid >> 6;
    int idx = blockIdx.x * 1024 + tid;
    int v = (idx < N) ? counts[idx] : 0;
    int val = v;
    #pragma unroll
    for (int o = 1; o < 64; o <<= 1) {
        int t = __shfl_up(val, o);
        if (lane >= o) val += t;
    }
    if (lane == 63) wsum[wid] = val;
    __syncthreads();
    int woff = 0;
    #pragma unroll
    for (int w = 0; w < 16; w++) woff += (w < wid) ? wsum[w] : 0;
    if (idx < N) row_ptr[idx] = woff + val - v;
    if (tid == 1023) bsum[blockIdx.x] = woff + val;
}

__global__ void scan2(int* __restrict__ bsum, int* __restrict__ row_ptr, int nb, int N) {
    int lane = threadIdx.x;
    int v = (lane < nb) ? bsum[lane] : 0;
    int val = v;
    #pragma unroll
    for (int o = 1; o < 64; o <<= 1) {
        int t = __shfl_up(val, o);
        if (lane >= o) val += t;
    }
    if (lane < nb) bsum[lane] = val - v;
    if (lane == 63) row_ptr[N] = val;
}

__global__ __launch_bounds__(1024) void scan3(int* __restrict__ row_ptr,
                                              const int* __restrict__ bsum,
                                              int* __restrict__ cursor, int N) {
    int idx = blockIdx.x * 1024 + threadIdx.x;
    if (idx >= N) return;
    int r = row_ptr[idx] + bsum[blockIdx.x];
    row_ptr[idx] = r;
    cursor[idx] = r;
}

__global__ void scatter_kernel(const int* __restrict__ ei, int E, int N,
                               int* __restrict__ cursor,
                               int* __restrict__ csr_src, int* __restrict__ csr_dst) {
    int i = blockIdx.x * blockDim.x + threadIdx.x;
    if (i >= E + N) return;
    int s, d;
    if (i < E) { s = ei[i]; d = ei[E + i]; }
    else       { s = d = i - E; }
    int pos = atomicAdd(&cursor[d], 1);
    csr_src[pos] = s;
    csr_dst[pos] = d;
}

// ---------------- fp32 -> f16 tiled conversions ----------------
__global__ void conv_x(const float* __restrict__ in, half_t* __restrict__ xt, int total) {
    int t = blockIdx.x * blockDim.x + threadIdx.x;
    if (t >= total) return;
    int i = t >> 5, o = t & 31;
    const float* src = in + (size_t)i * 256 + o * 8;
    float4 v0 = *(const float4*)src;
    float4 v1 = *(const float4*)(src + 4);
    half_t q[8] __attribute__((aligned(16)));
    q[0] = (half_t)v0.x; q[1] = (half_t)v0.y; q[2] = (half_t)v0.z; q[3] = (half_t)v0.w;
    q[4] = (half_t)v1.x; q[5] = (half_t)v1.y; q[6] = (half_t)v1.z; q[7] = (half_t)v1.w;
    size_t dst = (size_t)(i >> 4) * 4096 + (o >> 2) * 512 + (o & 3) * 128 + (i & 15) * 8;
    *(half8v*)(xt + dst) = *(half8v*)q;
}

__global__ void conv_w(const float* __restrict__ W, half_t* __restrict__ wt, int total) {
    int idx = blockIdx.x * blockDim.x + threadIdx.x;
    if (idx >= total) return;   // total = L*4*4*8*64
    int Lr = idx & 63;
    int s  = (idx >> 6) & 7;
    int cb = (idx >> 9) & 3;
    int h  = (idx >> 11) & 3;
    int l  = idx >> 13;
    int col = h * 64 + cb * 16 + (Lr & 15);
    int k0  = 32 * s + (Lr >> 4) * 8;
    half_t q[8] __attribute__((aligned(16)));
    #pragma unroll
    for (int j = 0; j < 8; j++)
        q[j] = (half_t)W[(size_t)l * 65536 + (size_t)(k0 + j) * 256 + col];
    *(half8v*)(wt + (size_t)idx * 8) = *(half8v*)q;
}

// ---------------- persistent-B f16 MFMA GEMM + fused attention scores ----------------
__global__ __launch_bounds__(256) void gemm_f16(
    const half_t* __restrict__ At, const half_t* __restrict__ Wt,
    const float* __restrict__ asrc, const float* __restrict__ adst,
    half_t* __restrict__ hp, float* __restrict__ as_out, float* __restrict__ ad_out,
    int Npad) {
    __shared__ float sp[2][4][16], sd[2][4][16];
    int cb = threadIdx.x >> 6, lane = threadIdx.x & 63;
    int h = blockIdx.x & 3, pg = blockIdx.x >> 2;
    int rlo = lane & 15, q = lane >> 4;
    const half_t* pb = Wt + (size_t)h * 16384 + (size_t)cb * 4096 + lane * 8;

    half8v B[8];
    #pragma unroll
    for (int s = 0; s < 8; s++) B[s] = *(const half8v*)(pb + s * 512);

    float av = asrc[h * 64 + cb * 16 + rlo];
    float dv = adst[h * 64 + cb * 16 + rlo];
    half_t* hph = hp + (size_t)h * Npad * 64;

    #pragma unroll
    for (int pp = 0; pp < 4; pp++) {
        int p = pg * 4 + pp;
        const half_t* pa = At + (size_t)p * 4096 + lane * 8;

        f32x4 acc = (f32x4){0.f, 0.f, 0.f, 0.f};
        half8v A0 = *(const half8v*)(pa);
        half8v A1;
        #pragma unroll
        for (int s = 0; s < 8; s += 2) {
            A1 = *(const half8v*)(pa + (s + 1) * 512);
            acc = __builtin_amdgcn_mfma_f32_16x16x32_f16(A0, B[s], acc, 0, 0, 0);
            if (s < 6) A0 = *(const half8v*)(pa + (s + 2) * 512);
            acc = __builtin_amdgcn_mfma_f32_16x16x32_f16(A1, B[s + 1], acc, 0, 0, 0);
        }

        int grow = p * 16 + q * 4;
        #pragma unroll
        for (int i = 0; i < 4; i++)
            hph[(size_t)(grow + i) * 64 + cb * 16 + rlo] = (half_t)acc[i];

        float ps[4], pd[4];
        #pragma unroll
        for (int i = 0; i < 4; i++) { ps[i] = acc[i] * av; pd[i] = acc[i] * dv; }
        #pragma unroll
        for (int mask = 1; mask <= 8; mask <<= 1) {
            #pragma unroll
            for (int i = 0; i < 4; i++) {
                ps[i] += __shfl_xor(ps[i], mask);
                pd[i] += __shfl_xor(pd[i], mask);
            }
        }
        int par = pp & 1;
        if (rlo == 0) {
            #pragma unroll
            for (int i = 0; i < 4; i++) {
                sp[par][cb][q * 4 + i] = ps[i];
                sd[par][cb][q * 4 + i] = pd[i];
            }
        }
        __syncthreads();
        if (threadIdx.x < 16) {
            int r = threadIdx.x;
            float s_ = sp[par][0][r] + sp[par][1][r] + sp[par][2][r] + sp[par][3][r];
            float d_ = sd[par][0][r] + sd[par][1][r] + sd[par][2][r] + sd[par][3][r];
            as_out[(size_t)(p * 16 + r) * 4 + h] = s_;
            ad_out[(size_t)(p * 16 + r) * 4 + h] = d_;
        }
    }
}

// ---------------- edge-parallel alpha: exp(leaky(a_s[src]+a_d[dst]) - 8), head-major ----------------
__global__ __launch_bounds__(256) void alpha_kernel(
    const float* __restrict__ a_s, const float* __restrict__ a_d,
    const int* __restrict__ csr_src, const int* __restrict__ csr_dst,
    float* __restrict__ alpha, int Etot) {
    int j = blockIdx.x * blockDim.x + threadIdx.x;
    if (j >= Etot) return;
    int s = csr_src[j], d = csr_dst[j];
    float4 as4 = *(const float4*)&a_s[(size_t)s * 4];
    float4 ad4 = *(const float4*)&a_d[(size_t)d * 4];
    float e0 = as4.x + ad4.x, e1 = as4.y + ad4.y;
    float e2 = as4.z + ad4.z, e3 = as4.w + ad4.w;
    e0 = e0 > 0.f ? e0 : NEG_SLOPE * e0;
    e1 = e1 > 0.f ? e1 : NEG_SLOPE * e1;
    e2 = e2 > 0.f ? e2 : NEG_SLOPE * e2;
    e3 = e3 > 0.f ? e3 : NEG_SLOPE * e3;
    alpha[j]            = __expf(e0 - ESHIFT);
    alpha[Etot + j]     = __expf(e1 - ESHIFT);
    alpha[2 * Etot + j] = __expf(e2 - ESHIFT);
    alpha[3 * Etot + j] = __expf(e3 - ESHIFT);
}

// ---------------- GAT aggregation: head-phased grid, wave per (node, head) ----------------
// Phase A: 2 coalesced loads (csr_src, alpha[h]) -> LDS. Phase B: fma_mix gather + fused asum.
// Reduce: 3-stage xor over 8 slots (9 regs). Epilogue: full-lane cndmask select + ELU.
#define AGG_BODY(g)                                                          \
    {                                                                        \
        int e_ = (g) * 8 + es;                                               \
        int s_ = __float_as_int(pk[wv][e_][0]);                              \
        float a_ = pk[wv][e_][1];                                            \
        const uint4 w_ = *(const uint4*)(hpb + (size_t)s_ * 64);             \
        asum += a_;                                                          \
        fma_mix_pair(c0, c1, w_.x, a_);                                      \
        fma_mix_pair(c2, c3, w_.y, a_);                                      \
        fma_mix_pair(c4, c5, w_.z, a_);                                      \
        fma_mix_pair(c6, c7, w_.w, a_);                                      \
    }

__global__ __launch_bounds__(256) void gat_aggregate(
    const half_t* __restrict__ hp, const float* __restrict__ alpha,
    const int* __restrict__ row_ptr, const int* __restrict__ csr_src,
    const float* __restrict__ bias, half_t* __restrict__ hnext,
    int N, int Npad, int ngroups, int Etot) {
    __shared__ float pk[4][64][2];     // [wave][edge][{src_bits, alpha}]
    __shared__ half_t lds_o[4][64];
    int wv = threadIdx.x >> 6, lane = threadIdx.x & 63;
    int h = blockIdx.x / ngroups;
    int d = (blockIdx.x % ngroups) * 4 + wv;
    if (d >= N) return;
    int r0 = row_ptr[d], deg = row_ptr[d + 1] - r0;
    const float* alh = alpha + (size_t)h * Etot;
    const half_t* hph = hp + (size_t)h * Npad * 64;

    if (deg <= 64) {
        // phase A: coalesced loads into LDS
        if (lane < deg) {
            pk[wv][lane][0] = __int_as_float(csr_src[r0 + lane]);
            pk[wv][lane][1] = alh[r0 + lane];
        }
        // phase B: lane = (slot es 0..7, ch-octet chq 0..7)
        int es = lane >> 3, chq = lane & 7;
        const half_t* hpb = hph + chq * 8;
        float c0 = 0.f, c1 = 0.f, c2 = 0.f, c3 = 0.f;
        float c4 = 0.f, c5 = 0.f, c6 = 0.f, c7 = 0.f;
        float asum = 0.f;
        int full = deg >> 3;
        int g = 0;
        for (; g + 2 <= full; g += 2) { AGG_BODY(g) AGG_BODY(g + 1) }
        for (; g < full; g++) { AGG_BODY(g) }
        {   // guarded tail (deg & 7 edges)
            int e0 = full * 8 + es;
            if (e0 < deg) {
                int s_ = __float_as_int(pk[wv][e0][0]);
                float a_ = pk[wv][e0][1];
                const uint4 w_ = *(const uint4*)(hpb + (size_t)s_ * 64);
                asum += a_;
                fma_mix_pair(c0, c1, w_.x, a_);
                fma_mix_pair(c2, c3, w_.y, a_);
                fma_mix_pair(c4, c5, w_.z, a_);
                fma_mix_pair(c6, c7, w_.w, a_);
            }
        }
        // joint reduce over the 8 slots
        #pragma unroll
        for (int o = 8; o <= 32; o <<= 1) {
            c0 += __shfl_xor(c0, o); c1 += __shfl_xor(c1, o);
            c2 += __shfl_xor(c2, o); c3 += __shfl_xor(c3, o);
            c4 += __shfl_xor(c4, o); c5 += __shfl_xor(c5, o);
            c6 += __shfl_xor(c6, o); c7 += __shfl_xor(c7, o);
            asum += __shfl_xor(asum, o);
        }
        // full-lane epilogue: lane (es,chq) handles channel chq*8+es
        float inv = 1.0f / asum;
        float t0 = (es & 1) ? c1 : c0;
        float t1 = (es & 1) ? c3 : c2;
        float t2 = (es & 1) ? c5 : c4;
        float t3 = (es & 1) ? c7 : c6;
        float u0 = (es & 2) ? t1 : t0;
        float u1 = (es & 2) ? t3 : t2;
        float v  = (es & 4) ? u1 : u0;
        int ch = chq * 8 + es;
        v = v * inv + bias[h * 64 + ch];
        v = v > 0.f ? v : (__expf(v) - 1.0f);   // ELU
        lds_o[wv][ch] = (half_t)v;
        if (es == 0) {   // 8 lanes: chq -> octet store in tiled layout
            half8v ov = *(half8v*)&lds_o[wv][chq * 8];
            int o = h * 8 + chq;
            size_t dst = (size_t)(d >> 4) * 4096 + (o >> 2) * 512 + (o & 3) * 128 + (d & 15) * 8;
            *(half8v*)(hnext + dst) = ov;
        }
    } else {
        // fallback (deg > 64): serial recompute using alpha
        float ssum = 0.f;
        for (int i = lane; i < deg; i += 64) ssum += alh[r0 + i];
        #pragma unroll
        for (int o = 32; o; o >>= 1) ssum += __shfl_xor(ssum, o);
        float inv = 1.0f / ssum;
        float acc = 0.f;
        for (int i = 0; i < deg; i++) {
            int s = csr_src[r0 + i];
            acc += alh[r0 + i] * (float)hph[(size_t)s * 64 + lane];
        }
        float v = acc * inv + bias[h * 64 + lane];
        v = v > 0.f ? v : (__expf(v) - 1.0f);
        int c = h * 64 + lane;
        size_t dst = (size_t)(d >> 4) * 4096 + (c >> 5) * 512 + ((c >> 3) & 3) * 128 + (d & 15) * 8 + (c & 7);
        hnext[dst] = (half_t)v;
    }
}

// ---------------- pooling + output head ----------------
__global__ __launch_bounds__(256) void col_sum_f16(const half_t* __restrict__ hin,
                                                   float* __restrict__ partial, int N, int rows_per_blk) {
    int c = threadIdx.x;
    int r0 = blockIdx.x * rows_per_blk;
    int r1 = min(r0 + rows_per_blk, N);
    int coff = (c >> 5) * 512 + ((c >> 3) & 3) * 128 + (c & 7);
    float acc = 0.f;
    for (int r = r0; r < r1; r++)
        acc += (float)hin[(size_t)(r >> 4) * 4096 + coff + (r & 15) * 8];
    partial[(size_t)blockIdx.x * 256 + c] = acc;
}

__global__ __launch_bounds__(256) void final_kernel(const float* __restrict__ partial,
                                                    const float* __restrict__ Wout,
                                                    const float* __restrict__ bout,
                                                    float* __restrict__ out, float invN, int nb) {
    __shared__ float gl[256];
    int j = threadIdx.x;
    float s = 0.f;
    for (int b = 0; b < nb; b++) s += partial[(size_t)b * 256 + j];
    gl[j] = s;
    __syncthreads();
    float acc = 0.f;
    for (int i = 0; i < 256; i++) acc += gl[i] * Wout[i * 256 + j];
    out[j] = acc * invN + bout[j];
}

extern "C" void kernel_launch(void* const* d_in, const int* in_sizes, int n_in,
                              void* d_out, int out_size, void* d_ws, size_t ws_size,
                              hipStream_t stream) {
    const float* x       = (const float*)d_in[0];
    const int*   ei      = (const int*)d_in[1];
    const float* Ws      = (const float*)d_in[2];
    const float* att_src = (const float*)d_in[3];
    const float* att_dst = (const float*)d_in[4];
    const float* biases  = (const float*)d_in[5];
    const float* Wout    = (const float*)d_in[6];
    const float* bout    = (const float*)d_in[7];
    float* out = (float*)d_out;

    int N = in_sizes[0] / D;          // 20000
    int E = in_sizes[1] / 2;          // 320000
    int L = in_sizes[2] / (D * D);    // 4
    int Etot = E + N;                 // 340000
    int Npad = (N + 63) & ~63;        // 20032

    char* ws = (char*)d_ws;
    size_t off = 0;
    auto alloc = [&](size_t bytes) -> void* {
        void* p = ws + off;
        off = (off + bytes + 255) & ~(size_t)255;
        return p;
    };
    half_t* xt     = (half_t*)alloc((size_t)Npad * D * 2);   // tiled A / h
    half_t* hp     = (half_t*)alloc((size_t)Npad * D * 2);   // head-major hp
    float* a_s     = (float*)alloc((size_t)Npad * H * 4);    // node-major [n][4]
    float* a_d     = (float*)alloc((size_t)Npad * H * 4);
    half_t* wt     = (half_t*)alloc((size_t)L * D * D * 2);  // fragment-linear W
    float* alpha   = (float*)alloc((size_t)H * Etot * 4);    // head-major [h][Etot]
    int*   counts  = (int*)alloc((size_t)N * 4);
    int*   row_ptr = (int*)alloc((size_t)(N + 1) * 4);
    int*   cursor  = (int*)alloc((size_t)N * 4);
    int*   bsum    = (int*)alloc(64 * 4);
    int*   csr_src = (int*)alloc((size_t)Etot * 4);
    int*   csr_dst = (int*)alloc((size_t)Etot * 4);
    int rows_per_blk = 254;
    int nb_pool = (N + rows_per_blk - 1) / rows_per_blk;     // 79
    float* partial = (float*)alloc((size_t)nb_pool * 256 * 4);
    if (off > ws_size) return;

    int thr = 256;

    // ---- conversions (tiled) ----
    int xtot = N * 32;
    conv_x<<<(xtot + thr - 1) / thr, thr, 0, stream>>>(x, xt, xtot);
    int wtot = L * 4 * 4 * 8 * 64;
    conv_w<<<(wtot + thr - 1) / thr, thr, 0, stream>>>(Ws, wt, wtot);

    // ---- CSR build (parallel scan) ----
    hipMemsetAsync(counts, 0, (size_t)N * 4, stream);
    count_kernel<<<(Etot + thr - 1) / thr, thr, 0, stream>>>(ei, E, N, counts);
    int nb_scan = (N + 1023) / 1024;  // 20
    scan1<<<nb_scan, 1024, 0, stream>>>(counts, row_ptr, bsum, N);
    scan2<<<1, 64, 0, stream>>>(bsum, row_ptr, nb_scan, N);
    scan3<<<nb_scan, 1024, 0, stream>>>(row_ptr, bsum, cursor, N);
    scatter_kernel<<<(Etot + thr - 1) / thr, thr, 0, stream>>>(ei, E, N, cursor, csr_src, csr_dst);

    // ---- layers ----
    int gemm_blocks = (Npad / 64) * 4;   // 1252: (panel-group, head)
    int ngroups = (N + 3) / 4;           // 5000
    int agg_blocks = 4 * ngroups;        // head-phased
    for (int l = 0; l < L; l++) {
        gemm_f16<<<gemm_blocks, 256, 0, stream>>>(
            xt, wt + (size_t)l * D * D,
            att_src + (size_t)l * H * C, att_dst + (size_t)l * H * C,
            hp, a_s, a_d, Npad);
        alpha_kernel<<<(Etot + thr - 1) / thr, thr, 0, stream>>>(
            a_s, a_d, csr_src, csr_dst, alpha, Etot);
        gat_aggregate<<<agg_blocks, 256, 0, stream>>>(
            hp, alpha, row_ptr, csr_src, biases + (size_t)l * D, xt, N, Npad, ngroups, Etot);
    }

    // ---- pool + head ----
    col_sum_f16<<<nb_pool, thr, 0, stream>>>(xt, partial, N, rows_per_blk);
    final_kernel<<<1, thr, 0, stream>>>(partial, Wout, bout, out, 1.0f / (float)N, nb_pool);
}

// Round 16
// 272.109 us; speedup vs baseline: 1.1872x; 1.1872x over previous
//
#include <hip/hip_runtime.h>
#include <hip/hip_bf16.h>

#define H 4
#define C 64
#define D 256
#define NEG_SLOPE 0.2f
#define ESHIFT 8.0f

typedef _Float16 half_t;
typedef __attribute__((ext_vector_type(8))) _Float16 half8v;
typedef __attribute__((ext_vector_type(4))) float f32x4;

// Layouts:
//  - A / h ("xt"): fragment-linear tiled. panel = 16 rows; half-offset(r,c) =
//    (c>>5)*512 + ((c>>3)&3)*128 + r*8 + (c&7); wave frag load = panel*4096 + s*512 + lane*8.
//  - hp: HEAD-MAJOR hp[h][n][64].  a_s / a_d: NODE-MAJOR [n][4].

// c_lo += f16lo(w)*a; c_hi += f16hi(w)*a  -- exact f32 fma with f16 source
__device__ inline void fma_mix_pair(float& clo, float& chi, unsigned wu, float a) {
    asm("v_fma_mix_f32 %0, %2, %3, %0 op_sel_hi:[1,0,0]\n\t"
        "v_fma_mix_f32 %1, %2, %3, %1 op_sel:[1,0,0] op_sel_hi:[1,0,0]"
        : "+v"(clo), "+v"(chi)
        : "v"(wu), "v"(a));
}

// ---------------- CSR build ----------------
__global__ void count_kernel(const int* __restrict__ ei, int E, int N, int* __restrict__ counts) {
    int i = blockIdx.x * blockDim.x + threadIdx.x;
    if (i >= E + N) return;
    int d = (i < E) ? ei[E + i] : (i - E);
    atomicAdd(&counts[d], 1);
}

__global__ __launch_bounds__(1024) void scan1(const int* __restrict__ counts,
                                              int* __restrict__ row_ptr,
                                              int* __restrict__ bsum, int N) {
    __shared__ int wsum[16];
    int tid = threadIdx.x, lane = tid & 63, wid = tid >> 6;
    int idx = blockIdx.x * 1024 + tid;
    int v = (idx < N) ? counts[idx] : 0;
    int val = v;
    #pragma unroll
    for (int o = 1; o < 64; o <<= 1) {
        int t = __shfl_up(val, o);
        if (lane >= o) val += t;
    }
    if (lane == 63) wsum[wid] = val;
    __syncthreads();
    int woff = 0;
    #pragma unroll
    for (int w = 0; w < 16; w++) woff += (w < wid) ? wsum[w] : 0;
    if (idx < N) row_ptr[idx] = woff + val - v;
    if (tid == 1023) bsum[blockIdx.x] = woff + val;
}

__global__ void scan2(int* __restrict__ bsum, int* __restrict__ row_ptr, int nb, int N) {
    int lane = threadIdx.x;
    int v = (lane < nb) ? bsum[lane] : 0;
    int val = v;
    #pragma unroll
    for (int o = 1; o < 64; o <<= 1) {
        int t = __shfl_up(val, o);
        if (lane >= o) val += t;
    }
    if (lane < nb) bsum[lane] = val - v;
    if (lane == 63) row_ptr[N] = val;
}

__global__ __launch_bounds__(1024) void scan3(int* __restrict__ row_ptr,
                                              const int* __restrict__ bsum,
                                              int* __restrict__ cursor, int N) {
    int idx = blockIdx.x * 1024 + threadIdx.x;
    if (idx >= N) return;
    int r = row_ptr[idx] + bsum[blockIdx.x];
    row_ptr[idx] = r;
    cursor[idx] = r;
}

__global__ void scatter_kernel(const int* __restrict__ ei, int E, int N,
                               int* __restrict__ cursor, int* __restrict__ csr_src) {
    int i = blockIdx.x * blockDim.x + threadIdx.x;
    if (i >= E + N) return;
    int s, d;
    if (i < E) { s = ei[i]; d = ei[E + i]; }
    else       { s = d = i - E; }
    int pos = atomicAdd(&cursor[d], 1);
    csr_src[pos] = s;
}

// ---------------- fp32 -> f16 tiled conversions ----------------
__global__ void conv_x(const float* __restrict__ in, half_t* __restrict__ xt, int total) {
    int t = blockIdx.x * blockDim.x + threadIdx.x;
    if (t >= total) return;
    int i = t >> 5, o = t & 31;
    const float* src = in + (size_t)i * 256 + o * 8;
    float4 v0 = *(const float4*)src;
    float4 v1 = *(const float4*)(src + 4);
    half_t q[8] __attribute__((aligned(16)));
    q[0] = (half_t)v0.x; q[1] = (half_t)v0.y; q[2] = (half_t)v0.z; q[3] = (half_t)v0.w;
    q[4] = (half_t)v1.x; q[5] = (half_t)v1.y; q[6] = (half_t)v1.z; q[7] = (half_t)v1.w;
    size_t dst = (size_t)(i >> 4) * 4096 + (o >> 2) * 512 + (o & 3) * 128 + (i & 15) * 8;
    *(half8v*)(xt + dst) = *(half8v*)q;
}

__global__ void conv_w(const float* __restrict__ W, half_t* __restrict__ wt, int total) {
    int idx = blockIdx.x * blockDim.x + threadIdx.x;
    if (idx >= total) return;   // total = L*4*4*8*64
    int Lr = idx & 63;
    int s  = (idx >> 6) & 7;
    int cb = (idx >> 9) & 3;
    int h  = (idx >> 11) & 3;
    int l  = idx >> 13;
    int col = h * 64 + cb * 16 + (Lr & 15);
    int k0  = 32 * s + (Lr >> 4) * 8;
    half_t q[8] __attribute__((aligned(16)));
    #pragma unroll
    for (int j = 0; j < 8; j++)
        q[j] = (half_t)W[(size_t)l * 65536 + (size_t)(k0 + j) * 256 + col];
    *(half8v*)(wt + (size_t)idx * 8) = *(half8v*)q;
}

// ---------------- persistent-B f16 MFMA GEMM + fused attention scores ----------------
// grid = (Npad/64 panel-groups) x 4 heads, XCD-swizzled so the 4 head-blocks of a
// panel-group run on the SAME XCD (A fetched once into that L2). One barrier total.
__global__ __launch_bounds__(256) void gemm_f16(
    const half_t* __restrict__ At, const half_t* __restrict__ Wt,
    const float* __restrict__ asrc, const float* __restrict__ adst,
    half_t* __restrict__ hp, float* __restrict__ as_out, float* __restrict__ ad_out,
    int Npad) {
    __shared__ float sp[4][4][16], sd[4][4][16];
    // bijective XCD swizzle (m204): consecutive swz -> same XCD chunk
    int nwg = gridDim.x;
    int bq = nwg >> 3, br = nwg & 7;
    int xcd = blockIdx.x & 7, bidx = blockIdx.x >> 3;
    int swz = (xcd < br ? xcd * (bq + 1) : br * (bq + 1) + (xcd - br) * bq) + bidx;
    int cb = threadIdx.x >> 6, lane = threadIdx.x & 63;
    int h = swz & 3, pg = swz >> 2;
    int rlo = lane & 15, q = lane >> 4;
    const half_t* pb = Wt + (size_t)h * 16384 + (size_t)cb * 4096 + lane * 8;

    half8v B[8];
    #pragma unroll
    for (int s = 0; s < 8; s++) B[s] = *(const half8v*)(pb + s * 512);

    float av = asrc[h * 64 + cb * 16 + rlo];
    float dv = adst[h * 64 + cb * 16 + rlo];
    half_t* hph = hp + (size_t)h * Npad * 64;

    #pragma unroll
    for (int pp = 0; pp < 4; pp++) {
        int p = pg * 4 + pp;
        const half_t* pa = At + (size_t)p * 4096 + lane * 8;

        f32x4 acc = (f32x4){0.f, 0.f, 0.f, 0.f};
        half8v A0 = *(const half8v*)(pa);
        half8v A1;
        #pragma unroll
        for (int s = 0; s < 8; s += 2) {
            A1 = *(const half8v*)(pa + (s + 1) * 512);
            acc = __builtin_amdgcn_mfma_f32_16x16x32_f16(A0, B[s], acc, 0, 0, 0);
            if (s < 6) A0 = *(const half8v*)(pa + (s + 2) * 512);
            acc = __builtin_amdgcn_mfma_f32_16x16x32_f16(A1, B[s + 1], acc, 0, 0, 0);
        }

        int grow = p * 16 + q * 4;
        #pragma unroll
        for (int i = 0; i < 4; i++)
            hph[(size_t)(grow + i) * 64 + cb * 16 + rlo] = (half_t)acc[i];

        // per-wave score partials (shfl only, no barrier)
        float ps[4], pd[4];
        #pragma unroll
        for (int i = 0; i < 4; i++) { ps[i] = acc[i] * av; pd[i] = acc[i] * dv; }
        #pragma unroll
        for (int mask = 1; mask <= 8; mask <<= 1) {
            #pragma unroll
            for (int i = 0; i < 4; i++) {
                ps[i] += __shfl_xor(ps[i], mask);
                pd[i] += __shfl_xor(pd[i], mask);
            }
        }
        if (rlo == 0) {
            #pragma unroll
            for (int i = 0; i < 4; i++) {
                sp[pp][cb][q * 4 + i] = ps[i];
                sd[pp][cb][q * 4 + i] = pd[i];
            }
        }
    }
    __syncthreads();   // ONE barrier for all 4 panels
    if (threadIdx.x < 64) {
        int pp = threadIdx.x >> 4, r = threadIdx.x & 15;
        float s_ = sp[pp][0][r] + sp[pp][1][r] + sp[pp][2][r] + sp[pp][3][r];
        float d_ = sd[pp][0][r] + sd[pp][1][r] + sd[pp][2][r] + sd[pp][3][r];
        int grow = (pg * 4 + pp) * 16 + r;
        as_out[(size_t)grow * 4 + h] = s_;
        ad_out[(size_t)grow * 4 + h] = d_;
    }
}

// ---------------- GAT aggregation: ONE wave per node, all 4 heads; 8 gathers in flight ----------------
#define AGG_BODY(g)                                                          \
    {                                                                        \
        int e_ = 2 * (g) + es;                                               \
        int s_ = __float_as_int(pk[wv][e_][0]);                              \
        float a_ = pk[wv][e_][4 + hh];                                       \
        const uint4 w_ = *(const uint4*)(hpb + (size_t)s_ * 64);             \
        asum += a_;                                                          \
        fma_mix_pair(c0, c1, w_.x, a_);                                      \
        fma_mix_pair(c2, c3, w_.y, a_);                                      \
        fma_mix_pair(c4, c5, w_.z, a_);                                      \
        fma_mix_pair(c6, c7, w_.w, a_);                                      \
    }

__global__ __launch_bounds__(256) void gat_aggregate(
    const half_t* __restrict__ hp, const float* __restrict__ as_, const float* __restrict__ ad_,
    const int* __restrict__ row_ptr, const int* __restrict__ csr_src,
    const float* __restrict__ bias, half_t* __restrict__ hnext, int N, int Npad) {
    __shared__ float pk[4][64][8];   // [wave][edge][{s_bits, -, -, -, e0,e1,e2,e3}]
    int wv = threadIdx.x >> 6, lane = threadIdx.x & 63;
    int d = blockIdx.x * 4 + wv;
    if (d >= N) return;
    int r0 = row_ptr[d], deg = row_ptr[d + 1] - r0;
    float4 adv = *(const float4*)&ad_[(size_t)d * 4];

    if (deg <= 64) {
        // phase A
        if (lane < deg) {
            int s = csr_src[r0 + lane];
            float4 as4 = *(const float4*)&as_[(size_t)s * 4];
            float e0 = as4.x + adv.x, e1 = as4.y + adv.y;
            float e2 = as4.z + adv.z, e3 = as4.w + adv.w;
            e0 = e0 > 0.f ? e0 : NEG_SLOPE * e0;
            e1 = e1 > 0.f ? e1 : NEG_SLOPE * e1;
            e2 = e2 > 0.f ? e2 : NEG_SLOPE * e2;
            e3 = e3 > 0.f ? e3 : NEG_SLOPE * e3;
            float4 ex;
            ex.x = __expf(e0 - ESHIFT);
            ex.y = __expf(e1 - ESHIFT);
            ex.z = __expf(e2 - ESHIFT);
            ex.w = __expf(e3 - ESHIFT);
            pk[wv][lane][0] = __int_as_float(s);
            *(float4*)&pk[wv][lane][4] = ex;
        }

        // phase B: lane = (head hh, slot es, ch-octet chq); 8-deep in-flight gathers
        int hh = lane >> 4;
        int es = (lane >> 3) & 1;
        int chq = lane & 7;
        const half_t* hpb = hp + (size_t)hh * Npad * 64 + chq * 8;
        float c0 = 0.f, c1 = 0.f, c2 = 0.f, c3 = 0.f;
        float c4 = 0.f, c5 = 0.f, c6 = 0.f, c7 = 0.f;
        float asum = 0.f;
        int full = deg >> 1;
        int g = 0;
        for (; g + 8 <= full; g += 8) {
            AGG_BODY(g)     AGG_BODY(g + 1) AGG_BODY(g + 2) AGG_BODY(g + 3)
            AGG_BODY(g + 4) AGG_BODY(g + 5) AGG_BODY(g + 6) AGG_BODY(g + 7)
        }
        for (; g + 4 <= full; g += 4) {
            AGG_BODY(g) AGG_BODY(g + 1) AGG_BODY(g + 2) AGG_BODY(g + 3)
        }
        for (; g < full; g++) { AGG_BODY(g) }
        if ((deg & 1) && es == 0) {       // odd tail
            int e_ = deg - 1;
            int s_ = __float_as_int(pk[wv][e_][0]);
            float a_ = pk[wv][e_][4 + hh];
            const uint4 w_ = *(const uint4*)(hpb + (size_t)s_ * 64);
            asum += a_;
            fma_mix_pair(c0, c1, w_.x, a_);
            fma_mix_pair(c2, c3, w_.y, a_);
            fma_mix_pair(c4, c5, w_.z, a_);
            fma_mix_pair(c6, c7, w_.w, a_);
        }
        // single-stage reduce across the 2 slots
        c0 += __shfl_xor(c0, 8); c1 += __shfl_xor(c1, 8);
        c2 += __shfl_xor(c2, 8); c3 += __shfl_xor(c3, 8);
        c4 += __shfl_xor(c4, 8); c5 += __shfl_xor(c5, 8);
        c6 += __shfl_xor(c6, 8); c7 += __shfl_xor(c7, 8);
        asum += __shfl_xor(asum, 8);
        // epilogue: es==0 lanes (hh,chq) own octet o = hh*8+chq
        if (!(lane & 8)) {
            float inv = 1.0f / asum;
            int o = hh * 8 + chq;
            const float* bp = bias + o * 8;
            float vv[8] = {c0, c1, c2, c3, c4, c5, c6, c7};
            half_t oh[8] __attribute__((aligned(16)));
            #pragma unroll
            for (int j = 0; j < 8; j++) {
                float v = vv[j] * inv + bp[j];
                v = v > 0.f ? v : (__expf(v) - 1.0f);   // ELU
                oh[j] = (half_t)v;
            }
            size_t dst = (size_t)(d >> 4) * 4096 + (o >> 2) * 512 + (o & 3) * 128 + (d & 15) * 8;
            *(half8v*)(hnext + dst) = *(half8v*)oh;
        }
    } else {
        // fallback (deg > 64): per-head serial recompute (rare/never for this data)
        float advA[4] = {adv.x, adv.y, adv.z, adv.w};
        #pragma unroll
        for (int hh = 0; hh < 4; hh++) {
            float advh = advA[hh];
            float ssum = 0.f;
            for (int i = lane; i < deg; i += 64) {
                int s = csr_src[r0 + i];
                float e = as_[(size_t)s * 4 + hh] + advh;
                e = e > 0.f ? e : NEG_SLOPE * e;
                ssum += __expf(e - ESHIFT);
            }
            #pragma unroll
            for (int o = 32; o; o >>= 1) ssum += __shfl_xor(ssum, o);
            float inv = 1.0f / ssum;
            const half_t* hph = hp + (size_t)hh * Npad * 64;
            float acc = 0.f;
            for (int i = 0; i < deg; i++) {
                int s = csr_src[r0 + i];
                float e = as_[(size_t)s * 4 + hh] + advh;
                e = e > 0.f ? e : NEG_SLOPE * e;
                acc += __expf(e - ESHIFT) * (float)hph[(size_t)s * 64 + lane];
            }
            float v = acc * inv + bias[hh * 64 + lane];
            v = v > 0.f ? v : (__expf(v) - 1.0f);
            int c = hh * 64 + lane;
            size_t dst = (size_t)(d >> 4) * 4096 + (c >> 5) * 512 + ((c >> 3) & 3) * 128 + (d & 15) * 8 + (c & 7);
            hnext[dst] = (half_t)v;
        }
    }
}

// ---------------- pooling + output head ----------------
__global__ __launch_bounds__(256) void col_sum_f16(const half_t* __restrict__ hin,
                                                   float* __restrict__ partial, int N, int rows_per_blk) {
    int c = threadIdx.x;
    int r0 = blockIdx.x * rows_per_blk;
    int r1 = min(r0 + rows_per_blk, N);
    int coff = (c >> 5) * 512 + ((c >> 3) & 3) * 128 + (c & 7);
    float acc = 0.f;
    for (int r = r0; r < r1; r++)
        acc += (float)hin[(size_t)(r >> 4) * 4096 + coff + (r & 15) * 8];
    partial[(size_t)blockIdx.x * 256 + c] = acc;
}

__global__ __launch_bounds__(256) void final_kernel(const float* __restrict__ partial,
                                                    const float* __restrict__ Wout,
                                                    const float* __restrict__ bout,
                                                    float* __restrict__ out, float invN, int nb) {
    __shared__ float gl[256];
    int j = threadIdx.x;
    float s = 0.f;
    for (int b = 0; b < nb; b++) s += partial[(size_t)b * 256 + j];
    gl[j] = s;
    __syncthreads();
    float acc = 0.f;
    for (int i = 0; i < 256; i++) acc += gl[i] * Wout[i * 256 + j];
    out[j] = acc * invN + bout[j];
}

extern "C" void kernel_launch(void* const* d_in, const int* in_sizes, int n_in,
                              void* d_out, int out_size, void* d_ws, size_t ws_size,
                              hipStream_t stream) {
    const float* x       = (const float*)d_in[0];
    const int*   ei      = (const int*)d_in[1];
    const float* Ws      = (const float*)d_in[2];
    const float* att_src = (const float*)d_in[3];
    const float* att_dst = (const float*)d_in[4];
    const float* biases  = (const float*)d_in[5];
    const float* Wout    = (const float*)d_in[6];
    const float* bout    = (const float*)d_in[7];
    float* out = (float*)d_out;

    int N = in_sizes[0] / D;          // 20000
    int E = in_sizes[1] / 2;          // 320000
    int L = in_sizes[2] / (D * D);    // 4
    int Etot = E + N;
    int Npad = (N + 63) & ~63;        // 20032 (1252 panels, 313 groups of 4)

    char* ws = (char*)d_ws;
    size_t off = 0;
    auto alloc = [&](size_t bytes) -> void* {
        void* p = ws + off;
        off = (off + bytes + 255) & ~(size_t)255;
        return p;
    };
    half_t* xt     = (half_t*)alloc((size_t)Npad * D * 2);   // tiled A / h
    half_t* hp     = (half_t*)alloc((size_t)Npad * D * 2);   // head-major hp
    float* a_s     = (float*)alloc((size_t)Npad * H * 4);    // node-major [n][4]
    float* a_d     = (float*)alloc((size_t)Npad * H * 4);
    half_t* wt     = (half_t*)alloc((size_t)L * D * D * 2);  // fragment-linear W
    int*   counts  = (int*)alloc((size_t)N * 4);
    int*   row_ptr = (int*)alloc((size_t)(N + 1) * 4);
    int*   cursor  = (int*)alloc((size_t)N * 4);
    int*   bsum    = (int*)alloc(64 * 4);
    int*   csr_src = (int*)alloc((size_t)Etot * 4);
    int rows_per_blk = 254;
    int nb_pool = (N + rows_per_blk - 1) / rows_per_blk;     // 79
    float* partial = (float*)alloc((size_t)nb_pool * 256 * 4);
    if (off > ws_size) return;

    int thr = 256;

    // ---- conversions (tiled) ----
    int xtot = N * 32;
    conv_x<<<(xtot + thr - 1) / thr, thr, 0, stream>>>(x, xt, xtot);
    int wtot = L * 4 * 4 * 8 * 64;
    conv_w<<<(wtot + thr - 1) / thr, thr, 0, stream>>>(Ws, wt, wtot);

    // ---- CSR build (parallel scan) ----
    hipMemsetAsync(counts, 0, (size_t)N * 4, stream);
    count_kernel<<<(Etot + thr - 1) / thr, thr, 0, stream>>>(ei, E, N, counts);
    int nb_scan = (N + 1023) / 1024;  // 20
    scan1<<<nb_scan, 1024, 0, stream>>>(counts, row_ptr, bsum, N);
    scan2<<<1, 64, 0, stream>>>(bsum, row_ptr, nb_scan, N);
    scan3<<<nb_scan, 1024, 0, stream>>>(row_ptr, bsum, cursor, N);
    scatter_kernel<<<(Etot + thr - 1) / thr, thr, 0, stream>>>(ei, E, N, cursor, csr_src);

    // ---- layers ----
    int gemm_blocks = (Npad / 64) * 4;   // 1252: (panel-group, head), XCD-swizzled in-kernel
    int agg_blocks = (N + 3) / 4;        // 5000: 4 nodes/block, 1 wave/node
    for (int l = 0; l < L; l++) {
        gemm_f16<<<gemm_blocks, 256, 0, stream>>>(
            xt, wt + (size_t)l * D * D,
            att_src + (size_t)l * H * C, att_dst + (size_t)l * H * C,
            hp, a_s, a_d, Npad);
        gat_aggregate<<<agg_blocks, 256, 0, stream>>>(
            hp, a_s, a_d, row_ptr, csr_src, biases + (size_t)l * D, xt, N, Npad);
    }

    // ---- pool + head ----
    col_sum_f16<<<nb_pool, thr, 0, stream>>>(xt, partial, N, rows_per_blk);
    final_kernel<<<1, thr, 0, stream>>>(partial, Wout, bout, out, 1.0f / (float)N, nb_pool);
}

// Round 17
// 265.081 us; speedup vs baseline: 1.2187x; 1.0265x over previous
//
#include <hip/hip_runtime.h>
#include <hip/hip_bf16.h>

#define H 4
#define C 64
#define D 256
#define NEG_SLOPE 0.2f
#define ESHIFT 8.0f
#define AGGC 48

typedef _Float16 half_t;
typedef __attribute__((ext_vector_type(8))) _Float16 half8v;
typedef __attribute__((ext_vector_type(4))) float f32x4;

// Layouts:
//  - A / h ("xt"): fragment-linear tiled. panel = 16 rows; half-offset(r,c) =
//    (c>>5)*512 + ((c>>3)&3)*128 + r*8 + (c&7); wave frag load = panel*4096 + s*512 + lane*8.
//  - hp: HEAD-MAJOR hp[h][n][64] (per-head slab 2.56MB fits one XCD 4MiB L2).
//  - a_s / a_d: NODE-MAJOR [n][4].

// c_lo += f16lo(w)*a; c_hi += f16hi(w)*a  -- exact f32 fma with f16 source
__device__ inline void fma_mix_pair(float& clo, float& chi, unsigned wu, float a) {
    asm("v_fma_mix_f32 %0, %2, %3, %0 op_sel_hi:[1,0,0]\n\t"
        "v_fma_mix_f32 %1, %2, %3, %1 op_sel:[1,0,0] op_sel_hi:[1,0,0]"
        : "+v"(clo), "+v"(chi)
        : "v"(wu), "v"(a));
}

// ---------------- CSR build ----------------
__global__ void count_kernel(const int* __restrict__ ei, int E, int N, int* __restrict__ counts) {
    int i = blockIdx.x * blockDim.x + threadIdx.x;
    if (i >= E + N) return;
    int d = (i < E) ? ei[E + i] : (i - E);
    atomicAdd(&counts[d], 1);
}

__global__ __launch_bounds__(1024) void scan1(const int* __restrict__ counts,
                                              int* __restrict__ row_ptr,
                                              int* __restrict__ bsum, int N) {
    __shared__ int wsum[16];
    int tid = threadIdx.x, lane = tid & 63, wid = tid >> 6;
    int idx = blockIdx.x * 1024 + tid;
    int v = (idx < N) ? counts[idx] : 0;
    int val = v;
    #pragma unroll
    for (int o = 1; o < 64; o <<= 1) {
        int t = __shfl_up(val, o);
        if (lane >= o) val += t;
    }
    if (lane == 63) wsum[wid] = val;
    __syncthreads();
    int woff = 0;
    #pragma unroll
    for (int w = 0; w < 16; w++) woff += (w < wid) ? wsum[w] : 0;
    if (idx < N) row_ptr[idx] = woff + val - v;
    if (tid == 1023) bsum[blockIdx.x] = woff + val;
}

__global__ void scan2(int* __restrict__ bsum, int* __restrict__ row_ptr, int nb, int N) {
    int lane = threadIdx.x;
    int v = (lane < nb) ? bsum[lane] : 0;
    int val = v;
    #pragma unroll
    for (int o = 1; o < 64; o <<= 1) {
        int t = __shfl_up(val, o);
        if (lane >= o) val += t;
    }
    if (lane < nb) bsum[lane] = val - v;
    if (lane == 63) row_ptr[N] = val;
}

__global__ __launch_bounds__(1024) void scan3(int* __restrict__ row_ptr,
                                              const int* __restrict__ bsum,
                                              int* __restrict__ cursor, int N) {
    int idx = blockIdx.x * 1024 + threadIdx.x;
    if (idx >= N) return;
    int r = row_ptr[idx] + bsum[blockIdx.x];
    row_ptr[idx] = r;
    cursor[idx] = r;
}

__global__ void scatter_kernel(const int* __restrict__ ei, int E, int N,
                               int* __restrict__ cursor, int* __restrict__ csr_src) {
    int i = blockIdx.x * blockDim.x + threadIdx.x;
    if (i >= E + N) return;
    int s, d;
    if (i < E) { s = ei[i]; d = ei[E + i]; }
    else       { s = d = i - E; }
    int pos = atomicAdd(&cursor[d], 1);
    csr_src[pos] = s;
}

// ---------------- fp32 -> f16 tiled conversions ----------------
__global__ void conv_x(const float* __restrict__ in, half_t* __restrict__ xt, int total) {
    int t = blockIdx.x * blockDim.x + threadIdx.x;
    if (t >= total) return;
    int i = t >> 5, o = t & 31;
    const float* src = in + (size_t)i * 256 + o * 8;
    float4 v0 = *(const float4*)src;
    float4 v1 = *(const float4*)(src + 4);
    half_t q[8] __attribute__((aligned(16)));
    q[0] = (half_t)v0.x; q[1] = (half_t)v0.y; q[2] = (half_t)v0.z; q[3] = (half_t)v0.w;
    q[4] = (half_t)v1.x; q[5] = (half_t)v1.y; q[6] = (half_t)v1.z; q[7] = (half_t)v1.w;
    size_t dst = (size_t)(i >> 4) * 4096 + (o >> 2) * 512 + (o & 3) * 128 + (i & 15) * 8;
    *(half8v*)(xt + dst) = *(half8v*)q;
}

__global__ void conv_w(const float* __restrict__ W, half_t* __restrict__ wt, int total) {
    int idx = blockIdx.x * blockDim.x + threadIdx.x;
    if (idx >= total) return;   // total = L*4*4*8*64
    int Lr = idx & 63;
    int s  = (idx >> 6) & 7;
    int cb = (idx >> 9) & 3;
    int h  = (idx >> 11) & 3;
    int l  = idx >> 13;
    int col = h * 64 + cb * 16 + (Lr & 15);
    int k0  = 32 * s + (Lr >> 4) * 8;
    half_t q[8] __attribute__((aligned(16)));
    #pragma unroll
    for (int j = 0; j < 8; j++)
        q[j] = (half_t)W[(size_t)l * 65536 + (size_t)(k0 + j) * 256 + col];
    *(half8v*)(wt + (size_t)idx * 8) = *(half8v*)q;
}

// ---------------- persistent-B f16 MFMA GEMM + fused attention scores ----------------
// grid = (Npad/64 panel-groups) x 4 heads, XCD-swizzled; one barrier total.
__global__ __launch_bounds__(256) void gemm_f16(
    const half_t* __restrict__ At, const half_t* __restrict__ Wt,
    const float* __restrict__ asrc, const float* __restrict__ adst,
    half_t* __restrict__ hp, float* __restrict__ as_out, float* __restrict__ ad_out,
    int Npad) {
    __shared__ float sp[4][4][16], sd[4][4][16];
    int nwg = gridDim.x;
    int bq = nwg >> 3, br = nwg & 7;
    int xcd = blockIdx.x & 7, bidx = blockIdx.x >> 3;
    int swz = (xcd < br ? xcd * (bq + 1) : br * (bq + 1) + (xcd - br) * bq) + bidx;
    int cb = threadIdx.x >> 6, lane = threadIdx.x & 63;
    int h = swz & 3, pg = swz >> 2;
    int rlo = lane & 15, q = lane >> 4;
    const half_t* pb = Wt + (size_t)h * 16384 + (size_t)cb * 4096 + lane * 8;

    half8v B[8];
    #pragma unroll
    for (int s = 0; s < 8; s++) B[s] = *(const half8v*)(pb + s * 512);

    float av = asrc[h * 64 + cb * 16 + rlo];
    float dv = adst[h * 64 + cb * 16 + rlo];
    half_t* hph = hp + (size_t)h * Npad * 64;

    #pragma unroll
    for (int pp = 0; pp < 4; pp++) {
        int p = pg * 4 + pp;
        const half_t* pa = At + (size_t)p * 4096 + lane * 8;

        f32x4 acc = (f32x4){0.f, 0.f, 0.f, 0.f};
        half8v A0 = *(const half8v*)(pa);
        half8v A1;
        #pragma unroll
        for (int s = 0; s < 8; s += 2) {
            A1 = *(const half8v*)(pa + (s + 1) * 512);
            acc = __builtin_amdgcn_mfma_f32_16x16x32_f16(A0, B[s], acc, 0, 0, 0);
            if (s < 6) A0 = *(const half8v*)(pa + (s + 2) * 512);
            acc = __builtin_amdgcn_mfma_f32_16x16x32_f16(A1, B[s + 1], acc, 0, 0, 0);
        }

        int grow = p * 16 + q * 4;
        #pragma unroll
        for (int i = 0; i < 4; i++)
            hph[(size_t)(grow + i) * 64 + cb * 16 + rlo] = (half_t)acc[i];

        float ps[4], pd[4];
        #pragma unroll
        for (int i = 0; i < 4; i++) { ps[i] = acc[i] * av; pd[i] = acc[i] * dv; }
        #pragma unroll
        for (int mask = 1; mask <= 8; mask <<= 1) {
            #pragma unroll
            for (int i = 0; i < 4; i++) {
                ps[i] += __shfl_xor(ps[i], mask);
                pd[i] += __shfl_xor(pd[i], mask);
            }
        }
        if (rlo == 0) {
            #pragma unroll
            for (int i = 0; i < 4; i++) {
                sp[pp][cb][q * 4 + i] = ps[i];
                sd[pp][cb][q * 4 + i] = pd[i];
            }
        }
    }
    __syncthreads();
    if (threadIdx.x < 64) {
        int pp = threadIdx.x >> 4, r = threadIdx.x & 15;
        float s_ = sp[pp][0][r] + sp[pp][1][r] + sp[pp][2][r] + sp[pp][3][r];
        float d_ = sd[pp][0][r] + sd[pp][1][r] + sd[pp][2][r] + sd[pp][3][r];
        int grow = (pg * 4 + pp) * 16 + r;
        as_out[(size_t)grow * 4 + h] = s_;
        ad_out[(size_t)grow * 4 + h] = d_;
    }
}

// ---------------- GAT aggregation: head-phased, wave = 4 nodes x 1 head ----------------
// grid = 4 heads x 1250 groups (16 nodes/block); per-XCD working set = one head slab
// (2.56MB, L2-resident). Quarter-wave (16 lanes = 2 edge-slots x 8 chan-octets) per node.
#define AGG_BODY(g)                                                          \
    {                                                                        \
        int e_ = 2 * (g) + es;                                               \
        int s_ = __float_as_int(pk[wv][nn][e_][0]);                          \
        float a_ = pk[wv][nn][e_][1];                                        \
        const uint4 w_ = *(const uint4*)(hpb + (size_t)s_ * 64);             \
        asum += a_;                                                          \
        fma_mix_pair(c0, c1, w_.x, a_);                                      \
        fma_mix_pair(c2, c3, w_.y, a_);                                      \
        fma_mix_pair(c4, c5, w_.z, a_);                                      \
        fma_mix_pair(c6, c7, w_.w, a_);                                      \
    }

__global__ __launch_bounds__(256) void gat_aggregate(
    const half_t* __restrict__ hp, const float* __restrict__ as_, const float* __restrict__ ad_,
    const int* __restrict__ row_ptr, const int* __restrict__ csr_src,
    const float* __restrict__ bias, half_t* __restrict__ hnext,
    int N, int Npad, int ngroups) {
    __shared__ float pk[4][4][AGGC][2];   // [wave][node][edge][{src_bits, alpha}]
    int wv = threadIdx.x >> 6, lane = threadIdx.x & 63;
    int h = blockIdx.x / ngroups;
    int db = (blockIdx.x % ngroups) * 16;
    int nn = lane >> 4;
    int d = db + wv * 4 + nn;
    if (d >= N) return;                   // quarter-level divergence, no barriers used
    int r0 = row_ptr[d], deg = row_ptr[d + 1] - r0;
    float adv = ad_[(size_t)d * 4 + h];
    const half_t* hph = hp + (size_t)h * Npad * 64;

    if (deg <= AGGC) {
        // phase A: 16 lanes/node load csr + a_s gather + exp -> LDS
        int le = lane & 15;
        #pragma unroll
        for (int k = 0; k < 3; k++) {
            int e = k * 16 + le;
            if (e < deg) {
                int s = csr_src[r0 + e];
                float ev = as_[(size_t)s * 4 + h] + adv;
                ev = ev > 0.f ? ev : NEG_SLOPE * ev;
                pk[wv][nn][e][0] = __int_as_float(s);
                pk[wv][nn][e][1] = __expf(ev - ESHIFT);
            }
        }
        // phase B: (es 0..1, chq 0..7) within the quarter
        int es = (lane >> 3) & 1, chq = lane & 7;
        const half_t* hpb = hph + chq * 8;
        float c0 = 0.f, c1 = 0.f, c2 = 0.f, c3 = 0.f;
        float c4 = 0.f, c5 = 0.f, c6 = 0.f, c7 = 0.f;
        float asum = 0.f;
        int full = deg >> 1;
        int g = 0;
        for (; g + 4 <= full; g += 4) {
            AGG_BODY(g) AGG_BODY(g + 1) AGG_BODY(g + 2) AGG_BODY(g + 3)
        }
        for (; g < full; g++) { AGG_BODY(g) }
        if ((deg & 1) && es == 0) {       // odd tail
            int e_ = deg - 1;
            int s_ = __float_as_int(pk[wv][nn][e_][0]);
            float a_ = pk[wv][nn][e_][1];
            const uint4 w_ = *(const uint4*)(hpb + (size_t)s_ * 64);
            asum += a_;
            fma_mix_pair(c0, c1, w_.x, a_);
            fma_mix_pair(c2, c3, w_.y, a_);
            fma_mix_pair(c4, c5, w_.z, a_);
            fma_mix_pair(c6, c7, w_.w, a_);
        }
        // reduce across the 2 slots (xor 8 stays within the 16-lane quarter)
        c0 += __shfl_xor(c0, 8); c1 += __shfl_xor(c1, 8);
        c2 += __shfl_xor(c2, 8); c3 += __shfl_xor(c3, 8);
        c4 += __shfl_xor(c4, 8); c5 += __shfl_xor(c5, 8);
        c6 += __shfl_xor(c6, 8); c7 += __shfl_xor(c7, 8);
        asum += __shfl_xor(asum, 8);
        // epilogue: es==0 lanes own octet o = h*8 + chq of node d
        if (es == 0) {
            float inv = 1.0f / asum;
            int o = h * 8 + chq;
            const float* bp = bias + h * 64 + chq * 8;
            float vv[8] = {c0, c1, c2, c3, c4, c5, c6, c7};
            half_t oh[8] __attribute__((aligned(16)));
            #pragma unroll
            for (int j = 0; j < 8; j++) {
                float v = vv[j] * inv + bp[j];
                v = v > 0.f ? v : (__expf(v) - 1.0f);   // ELU
                oh[j] = (half_t)v;
            }
            size_t dst = (size_t)(d >> 4) * 4096 + (o >> 2) * 512 + (o & 3) * 128 + (d & 15) * 8;
            *(half8v*)(hnext + dst) = *(half8v*)oh;
        }
    } else {
        // fallback (deg > AGGC): 16 lanes serial; lane owns 4 channels
        int lc = lane & 15;
        float cA = 0.f, cB = 0.f, cC = 0.f, cD = 0.f, asum = 0.f;
        for (int i = 0; i < deg; i++) {
            int s = csr_src[r0 + i];
            float ev = as_[(size_t)s * 4 + h] + adv;
            ev = ev > 0.f ? ev : NEG_SLOPE * ev;
            float a = __expf(ev - ESHIFT);
            asum += a;
            const uint2 w = *(const uint2*)(hph + (size_t)s * 64 + lc * 4);
            fma_mix_pair(cA, cB, w.x, a);
            fma_mix_pair(cC, cD, w.y, a);
        }
        float inv = 1.0f / asum;
        int c = h * 64 + lc * 4;
        float vv[4] = {cA, cB, cC, cD};
        half_t oh[4] __attribute__((aligned(8)));
        #pragma unroll
        for (int j = 0; j < 4; j++) {
            float v = vv[j] * inv + bias[c + j];
            v = v > 0.f ? v : (__expf(v) - 1.0f);
            oh[j] = (half_t)v;
        }
        size_t dst = (size_t)(d >> 4) * 4096 + (c >> 5) * 512 + ((c >> 3) & 3) * 128 + (d & 15) * 8 + (c & 7);
        *(uint2*)(hnext + dst) = *(uint2*)oh;
    }
}

// ---------------- pooling + output head ----------------
__global__ __launch_bounds__(256) void col_sum_f16(const half_t* __restrict__ hin,
                                                   float* __restrict__ partial, int N, int rows_per_blk) {
    int c = threadIdx.x;
    int r0 = blockIdx.x * rows_per_blk;
    int r1 = min(r0 + rows_per_blk, N);
    int coff = (c >> 5) * 512 + ((c >> 3) & 3) * 128 + (c & 7);
    float acc = 0.f;
    for (int r = r0; r < r1; r++)
        acc += (float)hin[(size_t)(r >> 4) * 4096 + coff + (r & 15) * 8];
    partial[(size_t)blockIdx.x * 256 + c] = acc;
}

__global__ __launch_bounds__(256) void final_kernel(const float* __restrict__ partial,
                                                    const float* __restrict__ Wout,
                                                    const float* __restrict__ bout,
                                                    float* __restrict__ out, float invN, int nb) {
    __shared__ float gl[256];
    int j = threadIdx.x;
    float s = 0.f;
    for (int b = 0; b < nb; b++) s += partial[(size_t)b * 256 + j];
    gl[j] = s;
    __syncthreads();
    float acc = 0.f;
    for (int i = 0; i < 256; i++) acc += gl[i] * Wout[i * 256 + j];
    out[j] = acc * invN + bout[j];
}

extern "C" void kernel_launch(void* const* d_in, const int* in_sizes, int n_in,
                              void* d_out, int out_size, void* d_ws, size_t ws_size,
                              hipStream_t stream) {
    const float* x       = (const float*)d_in[0];
    const int*   ei      = (const int*)d_in[1];
    const float* Ws      = (const float*)d_in[2];
    const float* att_src = (const float*)d_in[3];
    const float* att_dst = (const float*)d_in[4];
    const float* biases  = (const float*)d_in[5];
    const float* Wout    = (const float*)d_in[6];
    const float* bout    = (const float*)d_in[7];
    float* out = (float*)d_out;

    int N = in_sizes[0] / D;          // 20000
    int E = in_sizes[1] / 2;          // 320000
    int L = in_sizes[2] / (D * D);    // 4
    int Etot = E + N;
    int Npad = (N + 63) & ~63;        // 20032

    char* ws = (char*)d_ws;
    size_t off = 0;
    auto alloc = [&](size_t bytes) -> void* {
        void* p = ws + off;
        off = (off + bytes + 255) & ~(size_t)255;
        return p;
    };
    half_t* xt     = (half_t*)alloc((size_t)Npad * D * 2);   // tiled A / h
    half_t* hp     = (half_t*)alloc((size_t)Npad * D * 2);   // head-major hp
    float* a_s     = (float*)alloc((size_t)Npad * H * 4);    // node-major [n][4]
    float* a_d     = (float*)alloc((size_t)Npad * H * 4);
    half_t* wt     = (half_t*)alloc((size_t)L * D * D * 2);  // fragment-linear W
    int*   counts  = (int*)alloc((size_t)N * 4);
    int*   row_ptr = (int*)alloc((size_t)(N + 1) * 4);
    int*   cursor  = (int*)alloc((size_t)N * 4);
    int*   bsum    = (int*)alloc(64 * 4);
    int*   csr_src = (int*)alloc((size_t)Etot * 4);
    int rows_per_blk = 254;
    int nb_pool = (N + rows_per_blk - 1) / rows_per_blk;     // 79
    float* partial = (float*)alloc((size_t)nb_pool * 256 * 4);
    if (off > ws_size) return;

    int thr = 256;

    // ---- conversions (tiled) ----
    int xtot = N * 32;
    conv_x<<<(xtot + thr - 1) / thr, thr, 0, stream>>>(x, xt, xtot);
    int wtot = L * 4 * 4 * 8 * 64;
    conv_w<<<(wtot + thr - 1) / thr, thr, 0, stream>>>(Ws, wt, wtot);

    // ---- CSR build (parallel scan) ----
    hipMemsetAsync(counts, 0, (size_t)N * 4, stream);
    count_kernel<<<(Etot + thr - 1) / thr, thr, 0, stream>>>(ei, E, N, counts);
    int nb_scan = (N + 1023) / 1024;  // 20
    scan1<<<nb_scan, 1024, 0, stream>>>(counts, row_ptr, bsum, N);
    scan2<<<1, 64, 0, stream>>>(bsum, row_ptr, nb_scan, N);
    scan3<<<nb_scan, 1024, 0, stream>>>(row_ptr, bsum, cursor, N);
    scatter_kernel<<<(Etot + thr - 1) / thr, thr, 0, stream>>>(ei, E, N, cursor, csr_src);

    // ---- layers ----
    int gemm_blocks = (Npad / 64) * 4;   // 1252, XCD-swizzled in-kernel
    int ngroups = (N + 15) / 16;         // 1250
    int agg_blocks = 4 * ngroups;        // 5000, head-phased
    for (int l = 0; l < L; l++) {
        gemm_f16<<<gemm_blocks, 256, 0, stream>>>(
            xt, wt + (size_t)l * D * D,
            att_src + (size_t)l * H * C, att_dst + (size_t)l * H * C,
            hp, a_s, a_d, Npad);
        gat_aggregate<<<agg_blocks, 256, 0, stream>>>(
            hp, a_s, a_d, row_ptr, csr_src, biases + (size_t)l * D, xt, N, Npad, ngroups);
    }

    // ---- pool + head ----
    col_sum_f16<<<nb_pool, thr, 0, stream>>>(xt, partial, N, rows_per_blk);
    final_kernel<<<1, thr, 0, stream>>>(partial, Wout, bout, out, 1.0f / (float)N, nb_pool);
}